// Round 7
// baseline (869.897 us; speedup 1.0000x reference)
//
#include <hip/hip_runtime.h>
#include <hip/hip_fp16.h>
#include <hip/hip_cooperative_groups.h>

// MPM P2G: single cooperative kernel — zero / bucket-place / 4-z-node gather /
// overflow fixup, separated by grid.sync(). Cell-granular buckets of 16B
// quantized records {fx,fy,fz u16 fixed, m,vx,vy,vz fp16}, CAP=4 -> 64B/cell.
//
// node[g] = sum over particles in cells {g-1,g}^3 of trilinear w * (m, m*v)
// cell/node id: z + x*128 + y*128*128   (reference get_hash, dim==3)
//
// Gather: one thread owns 4 consecutive z-nodes; scans 2x2 xy columns x 5
// z-cells (20 cells / 4 nodes = 5 visits/node vs 8 in node-per-thread).
// Each record is unpacked ONCE and contributes to its 2 z-adjacent nodes via
// statically-indexed register accumulators (z loop fully unrolled).
// Every node written exactly once -> no memset of d_out, no atomics on it.
//
// Fallback 1 (coop launch rejected): same phases as 4 separate dispatches.
// Fallback 2 (ws too small): naive atomic scatter.

namespace cg = cooperative_groups;

#define GRID_DIM   128
#define NUM_CELLS  (GRID_DIM * GRID_DIM * GRID_DIM)   // 2,097,152
#define NCHUNKS    (NUM_CELLS / 4)                    // 524,288 z-chunks
#define INV_CELL   64.0f
#define OVF_MAX    65536
#define COOP_BLOCKS 1024
#define COOP_NT    (COOP_BLOCKS * 256)                // 262,144 threads

__device__ __forceinline__ int cell_id(int ix, int iy, int iz) {
    return iz + ix * GRID_DIM + iy * (GRID_DIM * GRID_DIM);
}
__device__ __forceinline__ unsigned int q16(float f) {
    int q = (int)(f * 65536.0f + 0.5f);
    return (unsigned int)min(q, 65535);
}
__device__ __forceinline__ unsigned int f2h(float f) {
    return (unsigned int)__half_as_ushort(__float2half(f));
}
__device__ __forceinline__ float h2f(unsigned int b) {
    return __half2float(__ushort_as_half((unsigned short)(b & 0xffffu)));
}

// ---- phase bodies (shared by coop kernel and fallback kernels) ------------
__device__ __forceinline__ void place_body(
    int i, const float* __restrict__ pos, const float* __restrict__ vel,
    const float* __restrict__ mass, unsigned int* __restrict__ cursors,
    uint4* __restrict__ buckets, int* __restrict__ ovf_cnt,
    int* __restrict__ ovf_list, int cap)
{
    float rx = pos[3 * i + 0] * INV_CELL;
    float ry = pos[3 * i + 1] * INV_CELL;
    float rz = pos[3 * i + 2] * INV_CELL;
    float bx = floorf(rx), by = floorf(ry), bz = floorf(rz);
    float fx = rx - bx, fy = ry - by, fz = rz - bz;   // in [0,1)
    int ix = min(max((int)bx, 0), GRID_DIM - 1);
    int iy = min(max((int)by, 0), GRID_DIM - 1);
    int iz = min(max((int)bz, 0), GRID_DIM - 1);
    int c = cell_id(ix, iy, iz);
    unsigned int s = atomicAdd(&cursors[c], 1u);
    if (s < (unsigned int)cap) {
        uint4 r;
        r.x = q16(fx) | (q16(fy) << 16);
        r.y = q16(fz) | (f2h(mass[i]) << 16);
        r.z = f2h(vel[3 * i + 0]) | (f2h(vel[3 * i + 1]) << 16);
        r.w = f2h(vel[3 * i + 2]);
        buckets[c * cap + (int)s] = r;
    } else {
        int o = atomicAdd(ovf_cnt, 1);
        if (o < OVF_MAX) ovf_list[o] = i;
    }
}

__device__ __forceinline__ void gather_body(
    int id, const uint4* __restrict__ buckets,
    const unsigned int* __restrict__ cursors, float4* __restrict__ out, int cap)
{
    // id -> 4-node z-chunk: zc fast (coalesced bucket walk + output stores)
    int zc = id & 31;
    int gx = (id >> 5) & (GRID_DIM - 1);
    int gy = id >> 12;
    int gz0 = zc << 2;

    float4 acc[4];
    #pragma unroll
    for (int k = 0; k < 4; ++k) acc[k] = make_float4(0.f, 0.f, 0.f, 0.f);

    int x0 = max(gx - 1, 0), y0 = max(gy - 1, 0);
    for (int cy = y0; cy <= gy; ++cy) {
        for (int cx = x0; cx <= gx; ++cx) {
            int cb = cx * GRID_DIM + cy * (GRID_DIM * GRID_DIM);
            bool xe = (cx == gx), ye = (cy == gy);
            #pragma unroll
            for (int d = -1; d <= 3; ++d) {           // cell z-offset, static
                if (d == -1 && gz0 == 0) continue;
                int c = cb + gz0 + d;
                int cnt = min((int)cursors[c], cap);
                if (cnt > 0) {
                    int base = c * cap;
                    #pragma unroll
                    for (int j = 0; j < 4; ++j) {     // predicated: MLP
                        if (j < cnt) {
                            uint4 r = buckets[base + j];
                            float fx = (float)(r.x & 0xffffu) * (1.0f / 65536.0f);
                            float fy = (float)(r.x >> 16)     * (1.0f / 65536.0f);
                            float fz = (float)(r.y & 0xffffu) * (1.0f / 65536.0f);
                            float m  = h2f(r.y >> 16);
                            float vx = h2f(r.z), vy = h2f(r.z >> 16), vz = h2f(r.w);
                            float wx = xe ? (1.0f - fx) : fx;
                            float wy = ye ? (1.0f - fy) : fy;
                            float wxym = wx * wy * m;
                            // cell cz feeds nodes cz (1-fz) and cz+1 (fz);
                            // d static after unroll -> acc indices static
                            if (d >= 0) {
                                float sm = wxym * (1.0f - fz);
                                acc[d].x += sm;
                                acc[d].y += sm * vx;
                                acc[d].z += sm * vy;
                                acc[d].w += sm * vz;
                            }
                            if (d < 3) {
                                float sm = wxym * fz;
                                acc[d + 1].x += sm;
                                acc[d + 1].y += sm * vx;
                                acc[d + 1].z += sm * vy;
                                acc[d + 1].w += sm * vz;
                            }
                        }
                    }
                }
            }
        }
    }
    float4* o = out + gz0 + gx * GRID_DIM + gy * (GRID_DIM * GRID_DIM);
    #pragma unroll
    for (int k = 0; k < 4; ++k) o[k] = acc[k];
}

__device__ __forceinline__ void fixup_body(
    int i, const float* __restrict__ pos, const float* __restrict__ vel,
    const float* __restrict__ mass, float* __restrict__ out)
{
    float px = pos[3 * i + 0] * INV_CELL;
    float py = pos[3 * i + 1] * INV_CELL;
    float pz = pos[3 * i + 2] * INV_CELL;
    float bx = floorf(px), by = floorf(py), bz = floorf(pz);
    float fx = px - bx, fy = py - by, fz = pz - bz;
    int ix = (int)bx, iy = (int)by, iz = (int)bz;
    float m = mass[i];
    float vx = vel[3 * i + 0], vy = vel[3 * i + 1], vz = vel[3 * i + 2];
    float wx[2] = { 1.0f - fx, fx }, wy[2] = { 1.0f - fy, fy }, wz[2] = { 1.0f - fz, fz };
    #pragma unroll
    for (int a = 0; a < 2; ++a)
        #pragma unroll
        for (int b = 0; b < 2; ++b)
            #pragma unroll
            for (int c = 0; c < 2; ++c) {
                int h = cell_id(ix + a, iy + b, iz + c);
                bool valid = (h >= 0) && (h < NUM_CELLS);
                int hc = min(max(h, 0), NUM_CELLS - 1);
                float s = valid ? (wx[a] * wy[b] * wz[c]) : 0.0f;
                float sm = s * m;
                float* cell = out + 4 * (size_t)hc;
                atomicAdd(cell + 0, sm);
                atomicAdd(cell + 1, sm * vx);
                atomicAdd(cell + 2, sm * vy);
                atomicAdd(cell + 3, sm * vz);
            }
}

// ---- cooperative mega-kernel: one dispatch, zero gaps ---------------------
__global__ __launch_bounds__(256, 4) void mega_kernel(
    const float* __restrict__ pos, const float* __restrict__ vel,
    const float* __restrict__ mass, unsigned int* __restrict__ cursors,
    uint4* __restrict__ buckets, int* __restrict__ ovf_cnt,
    int* __restrict__ ovf_list, float4* __restrict__ out, int cap, int n)
{
    cg::grid_group grid = cg::this_grid();
    int gtid = blockIdx.x * 256 + threadIdx.x;      // [0, COOP_NT)

    // phase 0: zero cursors + ovf_cnt (ws is re-poisoned before every call)
    uint4* c4 = (uint4*)cursors;                    // 524,288 uint4 = 2/thread
    uint4 z4 = make_uint4(0u, 0u, 0u, 0u);
    c4[gtid] = z4;
    c4[gtid + COOP_NT] = z4;
    if (gtid == 0) *ovf_cnt = 0;
    __threadfence();
    grid.sync();

    // phase 1: bucket placement
    for (int i = gtid; i < n; i += COOP_NT)
        place_body(i, pos, vel, mass, cursors, buckets, ovf_cnt, ovf_list, cap);
    __threadfence();
    grid.sync();

    // phase 2: gather (writes every node exactly once)
    for (int id = gtid; id < NCHUNKS; id += COOP_NT)
        gather_body(id, buckets, cursors, out, cap);
    __threadfence();
    grid.sync();

    // phase 3: overflow fixup (rare)
    int total = min(*ovf_cnt, OVF_MAX);
    for (int k = gtid; k < total; k += COOP_NT)
        fixup_body(ovf_list[k], pos, vel, mass, (float*)out);
}

// ---- fallback multi-kernel path (if cooperative launch is rejected) -------
__global__ __launch_bounds__(256) void place_kernel(
    const float* __restrict__ pos, const float* __restrict__ vel,
    const float* __restrict__ mass, unsigned int* __restrict__ cursors,
    uint4* __restrict__ buckets, int* __restrict__ ovf_cnt,
    int* __restrict__ ovf_list, int cap, int n)
{
    int i = blockIdx.x * 256 + threadIdx.x;
    if (i < n)
        place_body(i, pos, vel, mass, cursors, buckets, ovf_cnt, ovf_list, cap);
}

__global__ __launch_bounds__(256) void zgather_kernel(
    const uint4* __restrict__ buckets, const unsigned int* __restrict__ cursors,
    float4* __restrict__ out, int cap)
{
    int id = blockIdx.x * 256 + threadIdx.x;
    if (id < NCHUNKS)
        gather_body(id, buckets, cursors, out, cap);
}

__global__ __launch_bounds__(256) void fixup_kernel(
    const float* __restrict__ pos, const float* __restrict__ vel,
    const float* __restrict__ mass, const int* __restrict__ ovf_cnt,
    const int* __restrict__ ovf_list, float* __restrict__ out)
{
    int total = min(*ovf_cnt, OVF_MAX);
    for (int k = blockIdx.x * 256 + threadIdx.x; k < total; k += gridDim.x * 256)
        fixup_body(ovf_list[k], pos, vel, mass, out);
}

// ---- last-resort naive scatter --------------------------------------------
__global__ __launch_bounds__(256) void p2g_scatter_kernel(
    const float* __restrict__ pos, const float* __restrict__ vel,
    const float* __restrict__ mass, float* __restrict__ out, int n)
{
    int i = blockIdx.x * blockDim.x + threadIdx.x;
    if (i >= n) return;
    float px = pos[3 * i + 0] * INV_CELL;
    float py = pos[3 * i + 1] * INV_CELL;
    float pz = pos[3 * i + 2] * INV_CELL;
    float bx = floorf(px), by = floorf(py), bz = floorf(pz);
    float fx = px - bx, fy = py - by, fz = pz - bz;
    int ix = (int)bx, iy = (int)by, iz = (int)bz;
    float m = mass[i];
    float vx = vel[3 * i + 0], vy = vel[3 * i + 1], vz = vel[3 * i + 2];
    float wx[2] = { 1.0f - fx, fx }, wy[2] = { 1.0f - fy, fy }, wz[2] = { 1.0f - fz, fz };
    #pragma unroll
    for (int a = 0; a < 2; ++a)
        #pragma unroll
        for (int b = 0; b < 2; ++b)
            #pragma unroll
            for (int c = 0; c < 2; ++c) {
                int h = cell_id(ix + a, iy + b, iz + c);
                bool valid = (h >= 0) && (h < NUM_CELLS);
                int hc = min(max(h, 0), NUM_CELLS - 1);
                float s = valid ? (wx[a] * wy[b] * wz[c]) : 0.0f;
                float sm = s * m;
                float* cell = out + 4 * (size_t)hc;
                atomicAdd(cell + 0, sm);
                atomicAdd(cell + 1, sm * vx);
                atomicAdd(cell + 2, sm * vy);
                atomicAdd(cell + 3, sm * vz);
            }
}

extern "C" void kernel_launch(void* const* d_in, const int* in_sizes, int n_in,
                              void* d_out, int out_size, void* d_ws, size_t ws_size,
                              hipStream_t stream) {
    const float* pos  = (const float*)d_in[0];
    const float* vel  = (const float*)d_in[1];
    const float* mass = (const float*)d_in[2];
    int n = in_sizes[2];
    int blocks = (n + 255) / 256;

    // ws: [cursors 8MB][ovf_cnt 256B][ovf_list 256KB][buckets cap*32MB]
    size_t off_ovfc = (size_t)NUM_CELLS * 4;
    size_t off_ovfl = off_ovfc + 256;
    size_t off_bkt  = off_ovfl + (size_t)OVF_MAX * 4;
    auto bucket_need = [&](int cap) {
        return off_bkt + (size_t)NUM_CELLS * cap * 16;
    };
    int cap = 0;
    if (ws_size >= bucket_need(4))      cap = 4;
    else if (ws_size >= bucket_need(3)) cap = 3;

    if (cap > 0) {
        char* ws = (char*)d_ws;
        unsigned int* cursors = (unsigned int*)ws;
        int* ovf_cnt   = (int*)(ws + off_ovfc);
        int* ovf_list  = (int*)(ws + off_ovfl);
        uint4* buckets = (uint4*)(ws + off_bkt);
        float4* outv   = (float4*)d_out;

        void* args[] = { (void*)&pos, (void*)&vel, (void*)&mass,
                         (void*)&cursors, (void*)&buckets, (void*)&ovf_cnt,
                         (void*)&ovf_list, (void*)&outv, (void*)&cap, (void*)&n };
        hipError_t e = hipLaunchCooperativeKernel(
            (const void*)mega_kernel, dim3(COOP_BLOCKS), dim3(256),
            args, 0, stream);
        if (e != hipSuccess) {
            // graph-capture or env rejected cooperative launch: same phases,
            // four dispatches (verified structure from R5)
            hipMemsetAsync(cursors, 0, off_ovfc + 256, stream);
            place_kernel<<<blocks, 256, 0, stream>>>(
                pos, vel, mass, cursors, buckets, ovf_cnt, ovf_list, cap, n);
            zgather_kernel<<<NCHUNKS / 256, 256, 0, stream>>>(
                buckets, cursors, outv, cap);
            fixup_kernel<<<32, 256, 0, stream>>>(pos, vel, mass, ovf_cnt,
                                                 ovf_list, (float*)d_out);
        }
    } else {
        hipMemsetAsync(d_out, 0, (size_t)out_size * sizeof(float), stream);
        p2g_scatter_kernel<<<blocks, 256, 0, stream>>>(pos, vel, mass,
                                                       (float*)d_out, n);
    }
}

// Round 8
// 225.229 us; speedup vs baseline: 3.8623x; 3.8623x over previous
//
#include <hip/hip_runtime.h>
#include <hip/hip_fp16.h>

// MPM P2G: cell buckets (16B quantized records) + 4-z-node-per-thread gather.
//
// node[g] = sum over particles in cells {g-1,g}^3 of trilinear w * (m, m*v)
// cell/node id: z + x*128 + y*128*128   (reference get_hash, dim==3)
//
// Pipeline (4 dispatches, R5-verified structure):
//   M  memset : cursors (8MB) + ovf_cnt, one contiguous memset
//   K1 place  : atomicAdd(cursor[cell]) -> slot; 16B record
//               {fx,fy,fz u16 fixed, m,vx,vy,vz fp16}. CAP=4 -> 64B/cell.
//   K2 zgather: one thread owns 4 consecutive z-nodes; scans 2x2 xy columns
//               x 5 z-cells (5 visits/node vs 8 in node-per-thread). Each
//               record unpacked ONCE, feeds its 2 z-adjacent nodes via
//               statically-indexed register accumulators. 524K threads.
//               Every node written exactly once -> no memset/atomics on d_out.
//   K3 fixup  : rare bucket-overflow particles, exact fp32 atomic scatter.
// Fallback (ws too small): naive atomic scatter.

#define GRID_DIM   128
#define NUM_CELLS  (GRID_DIM * GRID_DIM * GRID_DIM)   // 2,097,152
#define NCHUNKS    (NUM_CELLS / 4)                    // 524,288
#define INV_CELL   64.0f
#define OVF_MAX    65536

__device__ __forceinline__ int cell_id(int ix, int iy, int iz) {
    return iz + ix * GRID_DIM + iy * (GRID_DIM * GRID_DIM);
}
__device__ __forceinline__ unsigned int q16(float f) {
    int q = (int)(f * 65536.0f + 0.5f);
    return (unsigned int)min(q, 65535);
}
__device__ __forceinline__ unsigned int f2h(float f) {
    return (unsigned int)__half_as_ushort(__float2half(f));
}
__device__ __forceinline__ float h2f(unsigned int b) {
    return __half2float(__ushort_as_half((unsigned short)(b & 0xffffu)));
}

// ---- K1: bucket placement (identical to R5, verified 64us) ----------------
__global__ __launch_bounds__(256) void bucket_place_kernel(
    const float* __restrict__ pos, const float* __restrict__ vel,
    const float* __restrict__ mass, unsigned int* __restrict__ cursors,
    uint4* __restrict__ buckets, int* __restrict__ ovf_cnt,
    int* __restrict__ ovf_list, int cap, int n)
{
    int i = blockIdx.x * 256 + threadIdx.x;
    if (i >= n) return;
    float rx = pos[3 * i + 0] * INV_CELL;
    float ry = pos[3 * i + 1] * INV_CELL;
    float rz = pos[3 * i + 2] * INV_CELL;
    float bx = floorf(rx), by = floorf(ry), bz = floorf(rz);
    float fx = rx - bx, fy = ry - by, fz = rz - bz;   // in [0,1)
    int ix = min(max((int)bx, 0), GRID_DIM - 1);
    int iy = min(max((int)by, 0), GRID_DIM - 1);
    int iz = min(max((int)bz, 0), GRID_DIM - 1);
    int c = cell_id(ix, iy, iz);
    unsigned int s = atomicAdd(&cursors[c], 1u);
    if (s < (unsigned int)cap) {
        uint4 r;
        r.x = q16(fx) | (q16(fy) << 16);
        r.y = q16(fz) | (f2h(mass[i]) << 16);
        r.z = f2h(vel[3 * i + 0]) | (f2h(vel[3 * i + 1]) << 16);
        r.w = f2h(vel[3 * i + 2]);
        buckets[c * cap + (int)s] = r;
    } else {
        int o = atomicAdd(ovf_cnt, 1);
        if (o < OVF_MAX) ovf_list[o] = i;
    }
}

// ---- K2: 4-z-node gather ---------------------------------------------------
__global__ __launch_bounds__(256) void zgather_kernel(
    const uint4* __restrict__ buckets, const unsigned int* __restrict__ cursors,
    float4* __restrict__ out, int cap)
{
    int id = blockIdx.x * 256 + threadIdx.x;      // [0, NCHUNKS)
    // zc fast -> wave walks consecutive z-chunks (coalesced cursors/out)
    int zc = id & 31;
    int gx = (id >> 5) & (GRID_DIM - 1);
    int gy = id >> 12;
    int gz0 = zc << 2;                            // first owned node z

    float4 acc[4];
    #pragma unroll
    for (int k = 0; k < 4; ++k) acc[k] = make_float4(0.f, 0.f, 0.f, 0.f);

    int x0 = max(gx - 1, 0), y0 = max(gy - 1, 0);
    for (int cy = y0; cy <= gy; ++cy) {
        for (int cx = x0; cx <= gx; ++cx) {
            int cb = cx * GRID_DIM + cy * (GRID_DIM * GRID_DIM);
            bool xe = (cx == gx), ye = (cy == gy);
            #pragma unroll
            for (int d = -1; d <= 3; ++d) {       // cell z-offset (static)
                if (d == -1 && gz0 == 0) continue;
                int c = cb + gz0 + d;
                int cnt = min((int)cursors[c], cap);
                if (cnt > 0) {
                    int base = c * cap;
                    #pragma unroll
                    for (int j = 0; j < 4; ++j) { // predicated -> MLP
                        if (j < cnt) {
                            uint4 r = buckets[base + j];
                            float fx = (float)(r.x & 0xffffu) * (1.0f / 65536.0f);
                            float fy = (float)(r.x >> 16)     * (1.0f / 65536.0f);
                            float fz = (float)(r.y & 0xffffu) * (1.0f / 65536.0f);
                            float m  = h2f(r.y >> 16);
                            float vx = h2f(r.z), vy = h2f(r.z >> 16), vz = h2f(r.w);
                            float wx = xe ? (1.0f - fx) : fx;
                            float wy = ye ? (1.0f - fy) : fy;
                            float wxym = wx * wy * m;
                            // cell z feeds node z with (1-fz), node z+1 with fz
                            if (d >= 0) {
                                float sm = wxym * (1.0f - fz);
                                acc[d].x += sm;
                                acc[d].y += sm * vx;
                                acc[d].z += sm * vy;
                                acc[d].w += sm * vz;
                            }
                            if (d < 3) {
                                float sm = wxym * fz;
                                acc[d + 1].x += sm;
                                acc[d + 1].y += sm * vx;
                                acc[d + 1].z += sm * vy;
                                acc[d + 1].w += sm * vz;
                            }
                        }
                    }
                }
            }
        }
    }
    float4* o = out + gz0 + gx * GRID_DIM + gy * (GRID_DIM * GRID_DIM);
    #pragma unroll
    for (int k = 0; k < 4; ++k) o[k] = acc[k];
}

// ---- K3: overflow fixup (exact fp32, rare) --------------------------------
__global__ __launch_bounds__(256) void fixup_kernel(
    const float* __restrict__ pos, const float* __restrict__ vel,
    const float* __restrict__ mass, const int* __restrict__ ovf_cnt,
    const int* __restrict__ ovf_list, float* __restrict__ out)
{
    int total = min(*ovf_cnt, OVF_MAX);
    for (int k = blockIdx.x * 256 + threadIdx.x; k < total; k += gridDim.x * 256) {
        int i = ovf_list[k];
        float px = pos[3 * i + 0] * INV_CELL;
        float py = pos[3 * i + 1] * INV_CELL;
        float pz = pos[3 * i + 2] * INV_CELL;
        float bx = floorf(px), by = floorf(py), bz = floorf(pz);
        float fx = px - bx, fy = py - by, fz = pz - bz;
        int ix = (int)bx, iy = (int)by, iz = (int)bz;
        float m = mass[i];
        float vx = vel[3 * i + 0], vy = vel[3 * i + 1], vz = vel[3 * i + 2];
        float wx[2] = { 1.0f - fx, fx }, wy[2] = { 1.0f - fy, fy }, wz[2] = { 1.0f - fz, fz };
        #pragma unroll
        for (int a = 0; a < 2; ++a)
            #pragma unroll
            for (int b = 0; b < 2; ++b)
                #pragma unroll
                for (int c = 0; c < 2; ++c) {
                    int h = cell_id(ix + a, iy + b, iz + c);
                    bool valid = (h >= 0) && (h < NUM_CELLS);
                    int hc = min(max(h, 0), NUM_CELLS - 1);
                    float s = valid ? (wx[a] * wy[b] * wz[c]) : 0.0f;
                    float sm = s * m;
                    float* cell = out + 4 * (size_t)hc;
                    atomicAdd(cell + 0, sm);
                    atomicAdd(cell + 1, sm * vx);
                    atomicAdd(cell + 2, sm * vy);
                    atomicAdd(cell + 3, sm * vz);
                }
    }
}

// ---- fallback: naive atomic scatter ---------------------------------------
__global__ __launch_bounds__(256) void p2g_scatter_kernel(
    const float* __restrict__ pos, const float* __restrict__ vel,
    const float* __restrict__ mass, float* __restrict__ out, int n)
{
    int i = blockIdx.x * blockDim.x + threadIdx.x;
    if (i >= n) return;
    float px = pos[3 * i + 0] * INV_CELL;
    float py = pos[3 * i + 1] * INV_CELL;
    float pz = pos[3 * i + 2] * INV_CELL;
    float bx = floorf(px), by = floorf(py), bz = floorf(pz);
    float fx = px - bx, fy = py - by, fz = pz - bz;
    int ix = (int)bx, iy = (int)by, iz = (int)bz;
    float m = mass[i];
    float vx = vel[3 * i + 0], vy = vel[3 * i + 1], vz = vel[3 * i + 2];
    float wx[2] = { 1.0f - fx, fx }, wy[2] = { 1.0f - fy, fy }, wz[2] = { 1.0f - fz, fz };
    #pragma unroll
    for (int a = 0; a < 2; ++a)
        #pragma unroll
        for (int b = 0; b < 2; ++b)
            #pragma unroll
            for (int c = 0; c < 2; ++c) {
                int h = cell_id(ix + a, iy + b, iz + c);
                bool valid = (h >= 0) && (h < NUM_CELLS);
                int hc = min(max(h, 0), NUM_CELLS - 1);
                float s = valid ? (wx[a] * wy[b] * wz[c]) : 0.0f;
                float sm = s * m;
                float* cell = out + 4 * (size_t)hc;
                atomicAdd(cell + 0, sm);
                atomicAdd(cell + 1, sm * vx);
                atomicAdd(cell + 2, sm * vy);
                atomicAdd(cell + 3, sm * vz);
            }
}

extern "C" void kernel_launch(void* const* d_in, const int* in_sizes, int n_in,
                              void* d_out, int out_size, void* d_ws, size_t ws_size,
                              hipStream_t stream) {
    const float* pos  = (const float*)d_in[0];
    const float* vel  = (const float*)d_in[1];
    const float* mass = (const float*)d_in[2];
    int n = in_sizes[2];
    int blocks = (n + 255) / 256;

    // ws: [cursors 8MB][ovf_cnt 256B][ovf_list 256KB][buckets cap*32MB]
    size_t off_ovfc = (size_t)NUM_CELLS * 4;
    size_t off_ovfl = off_ovfc + 256;
    size_t off_bkt  = off_ovfl + (size_t)OVF_MAX * 4;
    auto bucket_need = [&](int cap) {
        return off_bkt + (size_t)NUM_CELLS * cap * 16;
    };
    int cap = 0;
    if (ws_size >= bucket_need(4))      cap = 4;
    else if (ws_size >= bucket_need(3)) cap = 3;

    if (cap > 0) {
        char* ws = (char*)d_ws;
        unsigned int* cursors = (unsigned int*)ws;
        int* ovf_cnt   = (int*)(ws + off_ovfc);
        int* ovf_list  = (int*)(ws + off_ovfl);
        uint4* buckets = (uint4*)(ws + off_bkt);

        hipMemsetAsync(cursors, 0, off_ovfc + 256, stream);   // cursors+ovf_cnt
        bucket_place_kernel<<<blocks, 256, 0, stream>>>(
            pos, vel, mass, cursors, buckets, ovf_cnt, ovf_list, cap, n);
        zgather_kernel<<<NCHUNKS / 256, 256, 0, stream>>>(
            buckets, cursors, (float4*)d_out, cap);
        fixup_kernel<<<32, 256, 0, stream>>>(pos, vel, mass, ovf_cnt,
                                             ovf_list, (float*)d_out);
    } else {
        hipMemsetAsync(d_out, 0, (size_t)out_size * sizeof(float), stream);
        p2g_scatter_kernel<<<blocks, 256, 0, stream>>>(pos, vel, mass,
                                                       (float*)d_out, n);
    }
}